// Round 3
// baseline (427.039 us; speedup 1.0000x reference)
//
#include <hip/hip_runtime.h>

// Problem constants: B=8, H=32, W=32, T=4, BS=3, D=768, SMAX=2, P=2560
// Output [B,H,W,T,BS,D] f32. Every (y,x,t) cell covered by exactly one patch.
//
// v3: scatter -> gather inversion.
//   Pass 1: build cell->global-patch-id map (8*4096 ints = 131 KB, in d_ws).
//   Pass 2: one block per output cell in raster order; gather token, nt-store.
//   Writes: one dense sequential sweep per XCD (bijective XCD swizzle keeps
//   each XCD on a contiguous 37.7 MB window). Reads: 4 interleaved monotone
//   streams per XCD; coarse tokens get same-XCD L2 reuse (cached loads).
//   Rationale: the v2 patch-order scatter wrote 9216 of every 36864 B per
//   t-slice sweep, re-opening every DRAM row 4x; the harness fill (1 dense
//   sweep) proves 6.4 TB/s on the same path.

constexpr int H_ = 32;
constexpr int W_ = 32;
constexpr int T_ = 4;
constexpr int BS_ = 3;
constexpr int D_ = 768;
constexpr int CD  = BS_ * D_;        // 2304 floats per cell
constexpr int CD4 = CD / 4;          // 576 float4 per cell
constexpr int BLOCK = 192;           // 3 waves; 576/192 == 3 f4 per thread
constexpr int BN_ = 8;
constexpr int CELLS = BN_ * H_ * W_ * T_;   // 32768
constexpr int NXCD = 8;

typedef float f4 __attribute__((ext_vector_type(4)));

// ---- Pass 1: cell -> global patch id --------------------------------------
__global__ __launch_bounds__(256) void build_map_kernel(
    const int4* __restrict__ pos,   // [B*P] (y, x, size, t)
    int* __restrict__ map,          // [B*H*W*T]
    int P)
{
    const int bp = blockIdx.x * 256 + threadIdx.x;
    if (bp >= BN_ * P) return;
    const int b = bp / P;
    const int4 q = pos[bp];
    const int y = q.x, x = q.y, size = q.z, t = q.w;
    const int c0 = (((b * H_ + y) * W_ + x) * T_) + t;
    map[c0] = bp;
    if (size == 2) {
        map[c0 + T_] = bp;               // (y, x+1)
        map[c0 + W_ * T_] = bp;          // (y+1, x)
        map[c0 + W_ * T_ + T_] = bp;     // (y+1, x+1)
    }
}

// ---- Pass 2: gather, one block per cell, raster-order writes --------------
__global__ __launch_bounds__(BLOCK) void apt_gather_kernel(
    const f4* __restrict__ tok,     // [B*P, CD4]
    const int* __restrict__ map,    // [CELLS]
    f4* __restrict__ out)           // [CELLS, CD4]
{
    const int n = blockIdx.x;
    // XCD-aware swizzle: scheduler round-robins block n -> XCD n%8; remap so
    // each XCD sweeps a contiguous cell range (dense sequential writes +
    // same-XCD L2 reuse for coarse tokens). CELLS % 8 == 0 -> bijective.
    const int cell = (n & (NXCD - 1)) * (CELLS / NXCD) + (n >> 3);

    const int pid = map[cell];      // uniform scalar load
    const f4* __restrict__ src = tok + (long)pid * CD4;
    f4* __restrict__ dst = out + (long)cell * CD4;

    const int tid = threadIdx.x;
    #pragma unroll
    for (int k = 0; k < CD4 / BLOCK; ++k) {
        const int i = tid + k * BLOCK;
        const f4 v = src[i];                    // cached: coarse reuse in L2
        __builtin_nontemporal_store(v, &dst[i]); // streaming write
    }
}

// ---- Fallback (v2 scatter) if workspace is too small ----------------------
__global__ __launch_bounds__(BLOCK) void apt_scatter_kernel_nt(
    const f4* __restrict__ tok, const int4* __restrict__ pos,
    f4* __restrict__ out, int P)
{
    const int bp = blockIdx.x;
    const int b  = bp / P;
    const int4 q = pos[bp];
    const int y = q.x, x = q.y, size = q.z, t = q.w;
    const f4* __restrict__ src = tok + (long)bp * CD4;
    const long csy = (long)W_ * T_ * CD4;
    const long csx = (long)T_ * CD4;
    const long base0 = ((((long)b * H_ + y) * W_ + x) * T_ + t) * CD4;
    const int tid = threadIdx.x;
    if (size == 1) {
        f4* __restrict__ dst = out + base0;
        #pragma unroll
        for (int k = 0; k < CD4 / BLOCK; ++k) {
            const int i = tid + k * BLOCK;
            const f4 v = __builtin_nontemporal_load(&src[i]);
            __builtin_nontemporal_store(v, &dst[i]);
        }
    } else {
        f4* __restrict__ d00 = out + base0;
        f4* __restrict__ d01 = out + base0 + csx;
        f4* __restrict__ d10 = out + base0 + csy;
        f4* __restrict__ d11 = out + base0 + csy + csx;
        #pragma unroll
        for (int k = 0; k < CD4 / BLOCK; ++k) {
            const int i = tid + k * BLOCK;
            const f4 v = __builtin_nontemporal_load(&src[i]);
            __builtin_nontemporal_store(v, &d00[i]);
            __builtin_nontemporal_store(v, &d01[i]);
            __builtin_nontemporal_store(v, &d10[i]);
            __builtin_nontemporal_store(v, &d11[i]);
        }
    }
}

extern "C" void kernel_launch(void* const* d_in, const int* in_sizes, int n_in,
                              void* d_out, int out_size, void* d_ws, size_t ws_size,
                              hipStream_t stream) {
    const f4*   tok = (const f4*)d_in[0];     // [B, P*BS, D] f32
    const int4* pos = (const int4*)d_in[1];   // [B, P, 4] i32

    const int P = in_sizes[1] / (BN_ * 4);    // 2560

    const size_t map_bytes = (size_t)CELLS * sizeof(int);
    if (d_ws != nullptr && ws_size >= map_bytes) {
        int* map = (int*)d_ws;
        const int total = BN_ * P;
        build_map_kernel<<<(total + 255) / 256, 256, 0, stream>>>(pos, map, P);
        apt_gather_kernel<<<CELLS, BLOCK, 0, stream>>>(tok, map, (f4*)d_out);
    } else {
        apt_scatter_kernel_nt<<<BN_ * P, BLOCK, 0, stream>>>(tok, pos, (f4*)d_out, P);
    }
}